// Round 6
// baseline (234.512 us; speedup 1.0000x reference)
//
#include <hip/hip_runtime.h>
#include <hip/hip_bf16.h>

#define TOK 64
#define DIMC 512

typedef __attribute__((ext_vector_type(8))) short v8s;   // 8 bf16 = 4 VGPRs
typedef __attribute__((ext_vector_type(4))) float v4f;   // MFMA 16x16 acc

#define MFMA16 __builtin_amdgcn_mfma_f32_16x16x32_bf16

__device__ __forceinline__ unsigned int f2ord(float f) {
  unsigned int u = __float_as_uint(f);
  return (u & 0x80000000u) ? ~u : (u | 0x80000000u);
}

__device__ __forceinline__ float gelu_exact(float x) {
  return 0.5f * x * (1.0f + erff(x * 0.70710678118654752440f));
}

__device__ __forceinline__ unsigned short f2bf(float x) {  // RNE
  unsigned int u = __float_as_uint(x);
  return (unsigned short)((u + 0x7FFFu + ((u >> 16) & 1u)) >> 16);
}
__device__ __forceinline__ float bf2f(unsigned short h) {
  return __uint_as_float((unsigned int)h << 16);
}

__device__ __forceinline__ void gl2lds16(const void* g, void* l) {
  __builtin_amdgcn_global_load_lds((const __attribute__((address_space(1))) void*)g,
                                   (__attribute__((address_space(3))) void*)l,
                                   16, 0, 0);
}

// ---------------------------------------------------------------------------
// Kernel 1: fused prep. Roles by blockIdx.x:
//   [0,2048)      embed+pool -> hh/hl, init rowmin
//   [2048,2560)   w1 transpose+split
//   [2560,2816)   w2 transpose+split
//   [2816,6912)   codebook split + norms
// ---------------------------------------------------------------------------
__global__ __launch_bounds__(256) void k_prep(
    const int* __restrict__ zt, const int* __restrict__ ztp,
    const float* __restrict__ emb,
    unsigned short* __restrict__ hh, unsigned short* __restrict__ hl,
    unsigned long long* __restrict__ rowmin,
    const float* __restrict__ w1, unsigned short* __restrict__ w1th,
    unsigned short* __restrict__ w1tl,
    const float* __restrict__ w2, unsigned short* __restrict__ w2th,
    unsigned short* __restrict__ w2tl,
    const float* __restrict__ cb, unsigned short* __restrict__ ch,
    unsigned short* __restrict__ cl, float* __restrict__ cnorm) {
  __shared__ int codes[128];
  __shared__ float tbuf[32][33];
  const int bid = blockIdx.x;
  const int tid = threadIdx.x;

  if (bid < 2048) {
    // ---- embed + mean-pool ----
    const int b = bid;
    if (tid < 64) codes[tid] = zt[b * TOK + tid];
    else if (tid < 128) codes[tid] = ztp[b * TOK + (tid - 64)];
    if (tid == 0) rowmin[b] = 0xFFFFFFFFFFFFFFFFull;
    __syncthreads();
    const int half = tid >> 7;
    const int c4 = tid & 127;
    const float4* emb4 = (const float4*)emb;
    float4 s = make_float4(0.f, 0.f, 0.f, 0.f);
    #pragma unroll 8
    for (int t = 0; t < TOK; t++) {
      const int code = codes[half * TOK + t];
      const float4 v = emb4[code * 128 + c4];
      s.x += v.x; s.y += v.y; s.z += v.z; s.w += v.w;
    }
    const float inv = 1.0f / 64.0f;
    float f[4] = {s.x * inv, s.y * inv, s.z * inv, s.w * inv};
    unsigned short hi[4], lo[4];
    #pragma unroll
    for (int i = 0; i < 4; i++) {
      hi[i] = f2bf(f[i]);
      lo[i] = f2bf(f[i] - bf2f(hi[i]));
    }
    const int off = b * 1024 + half * 512 + c4 * 4;
    *(ushort4*)&hh[off] = make_ushort4(hi[0], hi[1], hi[2], hi[3]);
    *(ushort4*)&hl[off] = make_ushort4(lo[0], lo[1], lo[2], lo[3]);
  } else if (bid < 2816) {
    // ---- weight transpose + split ----
    const float* w; unsigned short *wth, *wtl; int Kd, N, k0, n0;
    if (bid < 2560) {
      const int i = bid - 2048;
      w = w1; wth = w1th; wtl = w1tl; Kd = 1024; N = 512;
      k0 = (i & 31) * 32; n0 = (i >> 5) * 32;
    } else {
      const int i = bid - 2560;
      w = w2; wth = w2th; wtl = w2tl; Kd = 512; N = 512;
      k0 = (i & 15) * 32; n0 = (i >> 4) * 32;
    }
    const int c = tid & 31, r = tid >> 5;  // r: 0..7
    #pragma unroll
    for (int i = 0; i < 4; i++)
      tbuf[r + i * 8][c] = w[(size_t)(k0 + r + i * 8) * N + n0 + c];
    __syncthreads();
    #pragma unroll
    for (int i = 0; i < 4; i++) {
      const float v = tbuf[c][r + i * 8];
      const unsigned short hi = f2bf(v);
      const unsigned short lo = f2bf(v - bf2f(hi));
      wth[(size_t)(n0 + r + i * 8) * Kd + k0 + c] = hi;
      wtl[(size_t)(n0 + r + i * 8) * Kd + k0 + c] = lo;
    }
  } else {
    // ---- codebook split + norms (one wave per row) ----
    const int row = (bid - 2816) * 4 + (tid >> 6);
    const int lane = tid & 63;
    const float4* cb4 = (const float4*)cb;
    const float4 va = cb4[row * 128 + lane * 2];
    const float4 vb = cb4[row * 128 + lane * 2 + 1];
    float s = va.x * va.x + va.y * va.y + va.z * va.z + va.w * va.w
            + vb.x * vb.x + vb.y * vb.y + vb.z * vb.z + vb.w * vb.w;
    float f[8] = {va.x, va.y, va.z, va.w, vb.x, vb.y, vb.z, vb.w};
    unsigned short hi[8], lo[8];
    #pragma unroll
    for (int i = 0; i < 8; i++) {
      hi[i] = f2bf(f[i]);
      lo[i] = f2bf(f[i] - bf2f(hi[i]));
    }
    ushort4* chp = (ushort4*)&ch[row * DIMC + lane * 8];
    ushort4* clp = (ushort4*)&cl[row * DIMC + lane * 8];
    chp[0] = make_ushort4(hi[0], hi[1], hi[2], hi[3]);
    chp[1] = make_ushort4(hi[4], hi[5], hi[6], hi[7]);
    clp[0] = make_ushort4(lo[0], lo[1], lo[2], lo[3]);
    clp[1] = make_ushort4(lo[4], lo[5], lo[6], lo[7]);
    #pragma unroll
    for (int off = 32; off > 0; off >>= 1) s += __shfl_down(s, off);
    if (lane == 0) cnorm[row] = s;
  }
}

// ---------------------------------------------------------------------------
// Kernel 2: split-bf16 MFMA GEMM, latency-optimized for small work:
// 32x64 tile (512 blocks = 2/CU), BK=32, DOUBLE-BUFFERED global_load_lds.
// ---------------------------------------------------------------------------
template <bool GELU>
__global__ __launch_bounds__(256) void k_gemm(const unsigned short* __restrict__ Ah_,
                                              const unsigned short* __restrict__ Al_,
                                              const unsigned short* __restrict__ Bh_,
                                              const unsigned short* __restrict__ Bl_,
                                              const float* __restrict__ bias,
                                              unsigned short* __restrict__ oh,
                                              unsigned short* __restrict__ ol,
                                              int Kd, int N) {
  __shared__ unsigned short AhS[2][32 * 32];   // 2 KB per buf
  __shared__ unsigned short AlS[2][32 * 32];
  __shared__ unsigned short BhS[2][64 * 32];   // 4 KB per buf
  __shared__ unsigned short BlS[2][64 * 32];

  const int tid = threadIdx.x;
  const int lane = tid & 63;
  const int wid = tid >> 6;
  const int m0 = blockIdx.x * 32;
  const int n0 = blockIdx.y * 64;

  const unsigned short* Ab_h = Ah_ + (size_t)m0 * Kd;
  const unsigned short* Ab_l = Al_ + (size_t)m0 * Kd;
  const unsigned short* Bb_h = Bh_ + (size_t)n0 * Kd;
  const unsigned short* Bb_l = Bl_ + (size_t)n0 * Kd;

  const int srow = lane >> 2;         // 0..15
  const int sk = (lane & 3) * 8;      // shorts
  const int wm = wid >> 1, wn = wid & 1;
  const int fr = lane & 15;
  const int fq = (lane >> 4) * 8;

  v4f acc[2];
  acc[0] = (v4f)(0.f);
  acc[1] = (v4f)(0.f);

  // stage one 32-k slice into buffer `b` (12 issues, 3 per wave)
  auto stage = [&](int b, int k0) {
    #pragma unroll
    for (int u = 0; u < 3; u++) {
      const int i = wid * 3 + u;   // wave-uniform
      const unsigned short* gs; unsigned short* ls; int rbase;
      if (i < 2)      { gs = Ab_h; ls = AhS[b]; rbase = i * 16; }
      else if (i < 4) { gs = Ab_l; ls = AlS[b]; rbase = (i - 2) * 16; }
      else if (i < 8) { gs = Bb_h; ls = BhS[b]; rbase = (i - 4) * 16; }
      else            { gs = Bb_l; ls = BlS[b]; rbase = (i - 8) * 16; }
      gl2lds16(gs + (size_t)(rbase + srow) * Kd + k0 + sk, ls + rbase * 32);
    }
  };

  stage(0, 0);
  int cur = 0;
  for (int k0 = 0; k0 < Kd; k0 += 32) {
    __syncthreads();               // drains vmcnt -> buf `cur` ready
    if (k0 + 32 < Kd) stage(cur ^ 1, k0 + 32);  // in flight during compute

    const int ar = (wm * 16 + fr) * 32 + fq;
    const v8s ah = *(const v8s*)&AhS[cur][ar];
    const v8s al = *(const v8s*)&AlS[cur][ar];
    #pragma unroll
    for (int nt = 0; nt < 2; nt++) {
      const int br = (wn * 32 + nt * 16 + fr) * 32 + fq;
      const v8s bh = *(const v8s*)&BhS[cur][br];
      const v8s bl = *(const v8s*)&BlS[cur][br];
      acc[nt] = MFMA16(ah, bh, acc[nt], 0, 0, 0);
      acc[nt] = MFMA16(ah, bl, acc[nt], 0, 0, 0);
      acc[nt] = MFMA16(al, bh, acc[nt], 0, 0, 0);
    }
    cur ^= 1;
  }

  // epilogue: C/D layout col=lane&15, row=(lane>>4)*4+reg
  const int col16 = lane & 15;
  const int q = lane >> 4;
  #pragma unroll
  for (int nt = 0; nt < 2; nt++) {
    const int col = n0 + wn * 32 + nt * 16 + col16;
    const float bv = bias[col];
    #pragma unroll
    for (int reg = 0; reg < 4; reg++) {
      const int row = m0 + wm * 16 + q * 4 + reg;
      float v = acc[nt][reg] + bv;
      if (GELU) v = gelu_exact(v);
      const unsigned short hi = f2bf(v);
      oh[(size_t)row * N + col] = hi;
      ol[(size_t)row * N + col] = f2bf(v - bf2f(hi));
    }
  }
}

// ---------------------------------------------------------------------------
// Kernel 3: VQ via split-bf16 MFMA GEMM — R5 structure (2-phase issue-early
// double-buffer, 256x256 tile, BK=32, conflict-free quad-swizzle: conflicts
// measured 0.0) re-partitioned for OCCUPANCY:
//   R5 post-mortem: LDS 128 KB -> 1 block/CU; 512 thr = 8 waves/CU =
//   2 waves/SIMD. Step window 6850 cy vs 3725 cy MFMA + 2304 cy LDS port —
//   nothing saturated => latency-bound from wave starvation.
//   Fix: SAME tile, SAME LDS, 1024 threads = 16 waves (4M x 4N, wave tile
//   64x64) -> 4 waves/SIMD. LDS reads 256/step/CU x 12cy = 3072 cy, still
//   under the 3725 cy matrix-pipe floor. 1024-thr block forces <=128
//   regs/wave: acc 16xv4f(64) + A-frags 8xv8s(32) + transient B(8) fits.
// Accumulation per acc unchanged (hh,hl,lh per k-step) and (score,id)-min
// merge is associative -> bitwise-identical results.
// score = ||c||^2 - 2*e.c
// ---------------------------------------------------------------------------
__global__ __launch_bounds__(1024) void k_vq(const unsigned short* __restrict__ eh,
                                             const unsigned short* __restrict__ el,
                                             const unsigned short* __restrict__ ch,
                                             const unsigned short* __restrict__ cl,
                                             const float* __restrict__ cnorm,
                                             unsigned long long* __restrict__ rowmin) {
  // per buffer (shorts): Ah[256*32] | Al[256*32] | Bh[256*32] | Bl[256*32]
  __shared__ unsigned short lds[2 * 32768];   // 128 KB

  const int tid = threadIdx.x;
  const int lane = tid & 63;
  const int wid = tid >> 6;                  // 0..15
  const int bid = blockIdx.x;
  const int x = (bid >> 3) & 7;              // 8 e-tiles (256 rows)
  const int y = (((bid >> 6) & 7) << 3) | (bid & 7);  // 64 cb-tiles (256 rows)
  const int r0 = x * 256;
  const int c0 = y * 256;

  const unsigned short* ehB = eh + (size_t)r0 * DIMC;
  const unsigned short* elB = el + (size_t)r0 * DIMC;
  const unsigned short* chB = ch + (size_t)c0 * DIMC;
  const unsigned short* clB = cl + (size_t)c0 * DIMC;

  const int srow = lane >> 2;                // 0..15
  // staging source quad swizzle: physical quad (lane&3) holds logical quad
  // (lane&3) ^ ((srow>>1)&3) = (lane&3) ^ ((lane>>3)&3)
  const int sk = ((lane & 3) ^ ((lane >> 3) & 3)) * 8;   // shorts
  const int wm = wid >> 2;                   // 0..3 (M, x64)
  const int wn = wid & 3;                    // 0..3 (N, x64)
  const int fr = lane & 15;
  const int q = lane >> 4;
  // fragment read quad swizzle: logical quad q of row (...+fr) lives at
  // physical quad q ^ ((fr>>1)&3)  (row-base terms are multiples of 16)
  const int fqs = (q ^ ((fr >> 1) & 3)) * 8;

  v4f acc[4][4];
  #pragma unroll
  for (int i = 0; i < 4; i++)
    #pragma unroll
    for (int jj = 0; jj < 4; jj++) acc[i][jj] = (v4f)(0.f);

  // 64 staging segments of 16 rows each: 4 per wave (wave-uniform i)
  const unsigned short* gp[4];
  int lo_[4];
  #pragma unroll
  for (int u = 0; u < 4; u++) {
    const int i = wid * 4 + u;
    const unsigned short* gs; int off, rbase;
    if (i < 16)      { gs = ehB; off = 0;     rbase = i * 16; }
    else if (i < 32) { gs = elB; off = 8192;  rbase = (i - 16) * 16; }
    else if (i < 48) { gs = chB; off = 16384; rbase = (i - 32) * 16; }
    else             { gs = clB; off = 24576; rbase = (i - 48) * 16; }
    gp[u] = gs + (size_t)(rbase + srow) * DIMC + sk;
    lo_[u] = off + rbase * 32;   // wave-uniform LDS short-offset (linear dest)
  }

  auto stage = [&](int buf, int k0) {   // 4 x global_load_lds dwordx4 per wave
    #pragma unroll
    for (int u = 0; u < 4; u++)
      gl2lds16(gp[u] + k0, lds + buf * 32768 + lo_[u]);
  };

  stage(0, 0);
  __syncthreads();                       // buf0 landed

  for (int t = 0; t < 16; ++t) {         // 16 = DIMC/32 K-steps
    if (t < 15) stage((t + 1) & 1, (t + 1) * 32);  // issue early; hides under compute

    const unsigned short* base = lds + (t & 1) * 32768;
    v8s ah[4], al[4];
    #pragma unroll
    for (int mt = 0; mt < 4; mt++) {
      const int ar = (wm * 64 + mt * 16 + fr) * 32 + fqs;
      ah[mt] = *(const v8s*)&base[ar];
      al[mt] = *(const v8s*)&base[8192 + ar];
    }
    __builtin_amdgcn_s_setprio(1);
    #pragma unroll
    for (int nt = 0; nt < 4; nt++) {
      const int br = (wn * 64 + nt * 16 + fr) * 32 + fqs;
      const v8s bh = *(const v8s*)&base[16384 + br];
      const v8s bl = *(const v8s*)&base[24576 + br];
      #pragma unroll
      for (int mt = 0; mt < 4; mt++) {
        acc[mt][nt] = MFMA16(ah[mt], bh, acc[mt][nt], 0, 0, 0);
        acc[mt][nt] = MFMA16(ah[mt], bl, acc[mt][nt], 0, 0, 0);
        acc[mt][nt] = MFMA16(al[mt], bh, acc[mt][nt], 0, 0, 0);
      }
    }
    __builtin_amdgcn_s_setprio(0);
    if (t < 15) __syncthreads();         // drains vmcnt -> next buf ready
  }

  // epilogue: C/D layout col=lane&15, row=(lane>>4)*4+reg
  const int col16 = lane & 15;
  float cn[4];
  #pragma unroll
  for (int nt = 0; nt < 4; nt++) cn[nt] = cnorm[c0 + wn * 64 + nt * 16 + col16];

  #pragma unroll
  for (int mt = 0; mt < 4; mt++) {
    #pragma unroll
    for (int reg = 0; reg < 4; reg++) {
      const int row = r0 + wm * 64 + mt * 16 + q * 4 + reg;
      float best = fmaf(-2.f, acc[mt][0][reg], cn[0]);
      int bid2 = c0 + wn * 64 + col16;
      #pragma unroll
      for (int nt = 1; nt < 4; nt++) {
        const float s = fmaf(-2.f, acc[mt][nt][reg], cn[nt]);
        const int id = c0 + wn * 64 + nt * 16 + col16;
        if (s < best) { best = s; bid2 = id; }
      }
      unsigned long long v =
          ((unsigned long long)f2ord(best) << 32) | (unsigned int)bid2;
      #pragma unroll
      for (int off = 8; off > 0; off >>= 1) {
        const unsigned long long o = __shfl_down(v, off, 16);
        if (o < v) v = o;
      }
      if (col16 == 0) atomicMin(&rowmin[row], v);
    }
  }
}

// ---------------------------------------------------------------------------
// Kernel 4: finalize — ids as float + gather q rows.
// ---------------------------------------------------------------------------
__global__ __launch_bounds__(64) void k_final(const unsigned long long* __restrict__ rowmin,
                                              const float* __restrict__ cb,
                                              float* __restrict__ out,
                                              int B) {
  const int b = blockIdx.x;
  const int t = threadIdx.x;
  const unsigned long long m = rowmin[b];
  const int id = (int)(unsigned int)(m & 0xFFFFFFFFull);
  if (t == 0) out[b] = (float)id;
  float4* q4 = (float4*)(out + B) + b * 128;
  const float4* cb4 = (const float4*)cb + (size_t)id * 128;
  q4[t] = cb4[t];
  q4[t + 64] = cb4[t + 64];
}

// ---------------------------------------------------------------------------
extern "C" void kernel_launch(void* const* d_in, const int* in_sizes, int n_in,
                              void* d_out, int out_size, void* d_ws, size_t ws_size,
                              hipStream_t stream) {
  const int* zt = (const int*)d_in[0];
  const int* ztp = (const int*)d_in[1];
  const float* emb = (const float*)d_in[2];
  const float* w1 = (const float*)d_in[3];
  const float* b1 = (const float*)d_in[4];
  const float* w2 = (const float*)d_in[5];
  const float* b2 = (const float*)d_in[6];
  const float* cb = (const float*)d_in[7];
  float* out = (float*)d_out;

  const int B = in_sizes[0] / TOK;        // 2048
  const int A = in_sizes[7] / DIMC;       // 16384

  char* p = (char*)d_ws;
  unsigned short* hh = (unsigned short*)p;  p += (size_t)B * 1024 * 2;
  unsigned short* hl = (unsigned short*)p;  p += (size_t)B * 1024 * 2;
  unsigned short* w1th = (unsigned short*)p; p += (size_t)512 * 1024 * 2;
  unsigned short* w1tl = (unsigned short*)p; p += (size_t)512 * 1024 * 2;
  unsigned short* w2th = (unsigned short*)p; p += (size_t)512 * 512 * 2;
  unsigned short* w2tl = (unsigned short*)p; p += (size_t)512 * 512 * 2;
  unsigned short* h1h = (unsigned short*)p; p += (size_t)B * DIMC * 2;
  unsigned short* h1l = (unsigned short*)p; p += (size_t)B * DIMC * 2;
  unsigned short* eh = (unsigned short*)p;  p += (size_t)B * DIMC * 2;
  unsigned short* el = (unsigned short*)p;  p += (size_t)B * DIMC * 2;
  unsigned short* ch = (unsigned short*)p;  p += (size_t)A * DIMC * 2;
  unsigned short* cl = (unsigned short*)p;  p += (size_t)A * DIMC * 2;
  float* cnorm = (float*)p;                 p += (size_t)A * 4;
  unsigned long long* rowmin = (unsigned long long*)p;

  k_prep<<<2816 + A / 4, 256, 0, stream>>>(zt, ztp, emb, hh, hl, rowmin,
                                           w1, w1th, w1tl, w2, w2th, w2tl,
                                           cb, ch, cl, cnorm);
  k_gemm<true><<<dim3(B / 32, 512 / 64), 256, 0, stream>>>(hh, hl, w1th, w1tl, b1, h1h, h1l, 1024, 512);
  k_gemm<false><<<dim3(B / 32, 512 / 64), 256, 0, stream>>>(h1h, h1l, w2th, w2tl, b2, eh, el, 512, 512);
  k_vq<<<(B / 256) * (A / 256), 1024, 0, stream>>>(eh, el, ch, cl, cnorm, rowmin);
  k_final<<<B, 64, 0, stream>>>(rowmin, cb, out, B);
}

// Round 7
// 223.432 us; speedup vs baseline: 1.0496x; 1.0496x over previous
//
#include <hip/hip_runtime.h>
#include <hip/hip_bf16.h>

#define TOK 64
#define DIMC 512

typedef __attribute__((ext_vector_type(8))) short v8s;   // 8 bf16 = 4 VGPRs
typedef __attribute__((ext_vector_type(4))) float v4f;   // MFMA 16x16 acc

#define MFMA16 __builtin_amdgcn_mfma_f32_16x16x32_bf16

__device__ __forceinline__ unsigned int f2ord(float f) {
  unsigned int u = __float_as_uint(f);
  return (u & 0x80000000u) ? ~u : (u | 0x80000000u);
}

__device__ __forceinline__ float gelu_exact(float x) {
  return 0.5f * x * (1.0f + erff(x * 0.70710678118654752440f));
}

__device__ __forceinline__ unsigned short f2bf(float x) {  // RNE
  unsigned int u = __float_as_uint(x);
  return (unsigned short)((u + 0x7FFFu + ((u >> 16) & 1u)) >> 16);
}
__device__ __forceinline__ float bf2f(unsigned short h) {
  return __uint_as_float((unsigned int)h << 16);
}

__device__ __forceinline__ void gl2lds16(const void* g, void* l) {
  __builtin_amdgcn_global_load_lds((const __attribute__((address_space(1))) void*)g,
                                   (__attribute__((address_space(3))) void*)l,
                                   16, 0, 0);
}

// ---------------------------------------------------------------------------
// Kernel 1: fused prep. Roles by blockIdx.x:
//   [0,2048)      embed+pool -> hh/hl, init rowmin
//   [2048,2560)   w1 transpose+split
//   [2560,2816)   w2 transpose+split
//   [2816,6912)   codebook split + norms
// ---------------------------------------------------------------------------
__global__ __launch_bounds__(256) void k_prep(
    const int* __restrict__ zt, const int* __restrict__ ztp,
    const float* __restrict__ emb,
    unsigned short* __restrict__ hh, unsigned short* __restrict__ hl,
    unsigned long long* __restrict__ rowmin,
    const float* __restrict__ w1, unsigned short* __restrict__ w1th,
    unsigned short* __restrict__ w1tl,
    const float* __restrict__ w2, unsigned short* __restrict__ w2th,
    unsigned short* __restrict__ w2tl,
    const float* __restrict__ cb, unsigned short* __restrict__ ch,
    unsigned short* __restrict__ cl, float* __restrict__ cnorm) {
  __shared__ int codes[128];
  __shared__ float tbuf[32][33];
  const int bid = blockIdx.x;
  const int tid = threadIdx.x;

  if (bid < 2048) {
    // ---- embed + mean-pool ----
    const int b = bid;
    if (tid < 64) codes[tid] = zt[b * TOK + tid];
    else if (tid < 128) codes[tid] = ztp[b * TOK + (tid - 64)];
    if (tid == 0) rowmin[b] = 0xFFFFFFFFFFFFFFFFull;
    __syncthreads();
    const int half = tid >> 7;
    const int c4 = tid & 127;
    const float4* emb4 = (const float4*)emb;
    float4 s = make_float4(0.f, 0.f, 0.f, 0.f);
    #pragma unroll 8
    for (int t = 0; t < TOK; t++) {
      const int code = codes[half * TOK + t];
      const float4 v = emb4[code * 128 + c4];
      s.x += v.x; s.y += v.y; s.z += v.z; s.w += v.w;
    }
    const float inv = 1.0f / 64.0f;
    float f[4] = {s.x * inv, s.y * inv, s.z * inv, s.w * inv};
    unsigned short hi[4], lo[4];
    #pragma unroll
    for (int i = 0; i < 4; i++) {
      hi[i] = f2bf(f[i]);
      lo[i] = f2bf(f[i] - bf2f(hi[i]));
    }
    const int off = b * 1024 + half * 512 + c4 * 4;
    *(ushort4*)&hh[off] = make_ushort4(hi[0], hi[1], hi[2], hi[3]);
    *(ushort4*)&hl[off] = make_ushort4(lo[0], lo[1], lo[2], lo[3]);
  } else if (bid < 2816) {
    // ---- weight transpose + split ----
    const float* w; unsigned short *wth, *wtl; int Kd, N, k0, n0;
    if (bid < 2560) {
      const int i = bid - 2048;
      w = w1; wth = w1th; wtl = w1tl; Kd = 1024; N = 512;
      k0 = (i & 31) * 32; n0 = (i >> 5) * 32;
    } else {
      const int i = bid - 2560;
      w = w2; wth = w2th; wtl = w2tl; Kd = 512; N = 512;
      k0 = (i & 15) * 32; n0 = (i >> 4) * 32;
    }
    const int c = tid & 31, r = tid >> 5;  // r: 0..7
    #pragma unroll
    for (int i = 0; i < 4; i++)
      tbuf[r + i * 8][c] = w[(size_t)(k0 + r + i * 8) * N + n0 + c];
    __syncthreads();
    #pragma unroll
    for (int i = 0; i < 4; i++) {
      const float v = tbuf[c][r + i * 8];
      const unsigned short hi = f2bf(v);
      const unsigned short lo = f2bf(v - bf2f(hi));
      wth[(size_t)(n0 + r + i * 8) * Kd + k0 + c] = hi;
      wtl[(size_t)(n0 + r + i * 8) * Kd + k0 + c] = lo;
    }
  } else {
    // ---- codebook split + norms (one wave per row) ----
    const int row = (bid - 2816) * 4 + (tid >> 6);
    const int lane = tid & 63;
    const float4* cb4 = (const float4*)cb;
    const float4 va = cb4[row * 128 + lane * 2];
    const float4 vb = cb4[row * 128 + lane * 2 + 1];
    float s = va.x * va.x + va.y * va.y + va.z * va.z + va.w * va.w
            + vb.x * vb.x + vb.y * vb.y + vb.z * vb.z + vb.w * vb.w;
    float f[8] = {va.x, va.y, va.z, va.w, vb.x, vb.y, vb.z, vb.w};
    unsigned short hi[8], lo[8];
    #pragma unroll
    for (int i = 0; i < 8; i++) {
      hi[i] = f2bf(f[i]);
      lo[i] = f2bf(f[i] - bf2f(hi[i]));
    }
    ushort4* chp = (ushort4*)&ch[row * DIMC + lane * 8];
    ushort4* clp = (ushort4*)&cl[row * DIMC + lane * 8];
    chp[0] = make_ushort4(hi[0], hi[1], hi[2], hi[3]);
    chp[1] = make_ushort4(hi[4], hi[5], hi[6], hi[7]);
    clp[0] = make_ushort4(lo[0], lo[1], lo[2], lo[3]);
    clp[1] = make_ushort4(lo[4], lo[5], lo[6], lo[7]);
    #pragma unroll
    for (int off = 32; off > 0; off >>= 1) s += __shfl_down(s, off);
    if (lane == 0) cnorm[row] = s;
  }
}

// ---------------------------------------------------------------------------
// Kernel 2: split-bf16 MFMA GEMM, latency-optimized for small work:
// 32x64 tile (512 blocks = 2/CU), BK=32, DOUBLE-BUFFERED global_load_lds.
// ---------------------------------------------------------------------------
template <bool GELU>
__global__ __launch_bounds__(256) void k_gemm(const unsigned short* __restrict__ Ah_,
                                              const unsigned short* __restrict__ Al_,
                                              const unsigned short* __restrict__ Bh_,
                                              const unsigned short* __restrict__ Bl_,
                                              const float* __restrict__ bias,
                                              unsigned short* __restrict__ oh,
                                              unsigned short* __restrict__ ol,
                                              int Kd, int N) {
  __shared__ unsigned short AhS[2][32 * 32];   // 2 KB per buf
  __shared__ unsigned short AlS[2][32 * 32];
  __shared__ unsigned short BhS[2][64 * 32];   // 4 KB per buf
  __shared__ unsigned short BlS[2][64 * 32];

  const int tid = threadIdx.x;
  const int lane = tid & 63;
  const int wid = tid >> 6;
  const int m0 = blockIdx.x * 32;
  const int n0 = blockIdx.y * 64;

  const unsigned short* Ab_h = Ah_ + (size_t)m0 * Kd;
  const unsigned short* Ab_l = Al_ + (size_t)m0 * Kd;
  const unsigned short* Bb_h = Bh_ + (size_t)n0 * Kd;
  const unsigned short* Bb_l = Bl_ + (size_t)n0 * Kd;

  const int srow = lane >> 2;         // 0..15
  const int sk = (lane & 3) * 8;      // shorts
  const int wm = wid >> 1, wn = wid & 1;
  const int fr = lane & 15;
  const int fq = (lane >> 4) * 8;

  v4f acc[2];
  acc[0] = (v4f)(0.f);
  acc[1] = (v4f)(0.f);

  // stage one 32-k slice into buffer `b` (12 issues, 3 per wave)
  auto stage = [&](int b, int k0) {
    #pragma unroll
    for (int u = 0; u < 3; u++) {
      const int i = wid * 3 + u;   // wave-uniform
      const unsigned short* gs; unsigned short* ls; int rbase;
      if (i < 2)      { gs = Ab_h; ls = AhS[b]; rbase = i * 16; }
      else if (i < 4) { gs = Ab_l; ls = AlS[b]; rbase = (i - 2) * 16; }
      else if (i < 8) { gs = Bb_h; ls = BhS[b]; rbase = (i - 4) * 16; }
      else            { gs = Bb_l; ls = BlS[b]; rbase = (i - 8) * 16; }
      gl2lds16(gs + (size_t)(rbase + srow) * Kd + k0 + sk, ls + rbase * 32);
    }
  };

  stage(0, 0);
  int cur = 0;
  for (int k0 = 0; k0 < Kd; k0 += 32) {
    __syncthreads();               // drains vmcnt -> buf `cur` ready
    if (k0 + 32 < Kd) stage(cur ^ 1, k0 + 32);  // in flight during compute

    const int ar = (wm * 16 + fr) * 32 + fq;
    const v8s ah = *(const v8s*)&AhS[cur][ar];
    const v8s al = *(const v8s*)&AlS[cur][ar];
    #pragma unroll
    for (int nt = 0; nt < 2; nt++) {
      const int br = (wn * 32 + nt * 16 + fr) * 32 + fq;
      const v8s bh = *(const v8s*)&BhS[cur][br];
      const v8s bl = *(const v8s*)&BlS[cur][br];
      acc[nt] = MFMA16(ah, bh, acc[nt], 0, 0, 0);
      acc[nt] = MFMA16(ah, bl, acc[nt], 0, 0, 0);
      acc[nt] = MFMA16(al, bh, acc[nt], 0, 0, 0);
    }
    cur ^= 1;
  }

  // epilogue: C/D layout col=lane&15, row=(lane>>4)*4+reg
  const int col16 = lane & 15;
  const int q = lane >> 4;
  #pragma unroll
  for (int nt = 0; nt < 2; nt++) {
    const int col = n0 + wn * 32 + nt * 16 + col16;
    const float bv = bias[col];
    #pragma unroll
    for (int reg = 0; reg < 4; reg++) {
      const int row = m0 + wm * 16 + q * 4 + reg;
      float v = acc[nt][reg] + bv;
      if (GELU) v = gelu_exact(v);
      const unsigned short hi = f2bf(v);
      oh[(size_t)row * N + col] = hi;
      ol[(size_t)row * N + col] = f2bf(v - bf2f(hi));
    }
  }
}

// ---------------------------------------------------------------------------
// Kernel 3: VQ via split-bf16 MFMA GEMM — R5 config (2-phase double-buffer,
// 256x256 tile, 512 thr = 8 waves 4M x 2N, wave tile 64x128, BK=32,
// conflict-free quad-swizzle: SQ_LDS_BANK_CONFLICT measured 0.0) with the
// K-step body REORDERED: reads-first -> stage -> MFMA -> barrier.
//
// R6 post-mortem: doubling occupancy delivered ZERO extra MFMA throughput
// (util x time constant) => limiter is per-step serialization, not TLP.
// Gap model: step 6900cy = MFMA 3725 + ~2800 non-overlapped LDS/staging.
// Two mechanisms, one fix:
//  (1) stage() BEFORE ds_reads lets the compiler insert a vmcnt(0) drain
//      ahead of the reads (can't prove the dbuf halves don't alias) —
//      staging latency exposed every step, "issue-early" nullified.
//  (2) read-cluster -> MFMA-cluster phase-lock (setprio reinforced it).
// New order: all 24 frag ds_reads issue FIRST (program order precedes the
// LDS writes -> no alias ordering), then 8 global_load_lds, then 96 MFMAs
// (~3725cy covers both lgkm waits and staging flight), then __syncthreads
// (vmcnt drain now nearly free). setprio dropped (null pre-phase-split).
// Same accumulation order -> bitwise-identical results.
// score = ||c||^2 - 2*e.c
// ---------------------------------------------------------------------------
__global__ __launch_bounds__(512, 2) void k_vq(const unsigned short* __restrict__ eh,
                                               const unsigned short* __restrict__ el,
                                               const unsigned short* __restrict__ ch,
                                               const unsigned short* __restrict__ cl,
                                               const float* __restrict__ cnorm,
                                               unsigned long long* __restrict__ rowmin) {
  // per buffer (shorts): Ah[256*32] | Al[256*32] | Bh[256*32] | Bl[256*32]
  __shared__ unsigned short lds[2 * 32768];   // 128 KB

  const int tid = threadIdx.x;
  const int lane = tid & 63;
  const int wid = tid >> 6;                  // 0..7
  const int bid = blockIdx.x;
  const int x = (bid >> 3) & 7;              // 8 e-tiles (256 rows)
  const int y = (((bid >> 6) & 7) << 3) | (bid & 7);  // 64 cb-tiles (256 rows)
  const int r0 = x * 256;
  const int c0 = y * 256;

  const unsigned short* ehB = eh + (size_t)r0 * DIMC;
  const unsigned short* elB = el + (size_t)r0 * DIMC;
  const unsigned short* chB = ch + (size_t)c0 * DIMC;
  const unsigned short* clB = cl + (size_t)c0 * DIMC;

  const int srow = lane >> 2;                // 0..15
  // staging source quad swizzle: physical quad (lane&3) holds logical quad
  // (lane&3) ^ ((srow>>1)&3) = (lane&3) ^ ((lane>>3)&3)
  const int sk = ((lane & 3) ^ ((lane >> 3) & 3)) * 8;   // shorts
  const int wm = wid >> 1;                   // 0..3 (M)
  const int wn = wid & 1;                    // 0..1 (N)
  const int fr = lane & 15;
  const int q = lane >> 4;
  // fragment read quad swizzle: logical quad q of row (...+fr) lives at
  // physical quad q ^ ((fr>>1)&3)  (row-base terms are multiples of 16)
  const int fqs = (q ^ ((fr >> 1) & 3)) * 8;

  v4f acc[4][8];
  #pragma unroll
  for (int i = 0; i < 4; i++)
    #pragma unroll
    for (int jj = 0; jj < 8; jj++) acc[i][jj] = (v4f)(0.f);

  // 64 staging segments of 16 rows each: 8 per wave (wave-uniform i)
  const unsigned short* gp[8];
  int lo_[8];
  #pragma unroll
  for (int u = 0; u < 8; u++) {
    const int i = wid * 8 + u;
    const unsigned short* gs; int off, rbase;
    if (i < 16)      { gs = ehB; off = 0;     rbase = i * 16; }
    else if (i < 32) { gs = elB; off = 8192;  rbase = (i - 16) * 16; }
    else if (i < 48) { gs = chB; off = 16384; rbase = (i - 32) * 16; }
    else             { gs = clB; off = 24576; rbase = (i - 48) * 16; }
    gp[u] = gs + (size_t)(rbase + srow) * DIMC + sk;
    lo_[u] = off + rbase * 32;   // wave-uniform LDS short-offset (linear dest)
  }

  auto stage = [&](int buf, int k0) {   // 8 x global_load_lds dwordx4 per wave
    #pragma unroll
    for (int u = 0; u < 8; u++)
      gl2lds16(gp[u] + k0, lds + buf * 32768 + lo_[u]);
  };

  stage(0, 0);
  __syncthreads();                       // buf0 landed

  for (int t = 0; t < 16; ++t) {         // 16 = DIMC/32 K-steps
    const unsigned short* base = lds + (t & 1) * 32768;

    // --- 1) ALL fragment reads first (before any LDS-writing op this step) ---
    v8s ah[4], al[4];
    #pragma unroll
    for (int mt = 0; mt < 4; mt++) {
      const int ar = (wm * 64 + mt * 16 + fr) * 32 + fqs;
      ah[mt] = *(const v8s*)&base[ar];
      al[mt] = *(const v8s*)&base[8192 + ar];
    }
    v8s bhf[8], blf[8];
    #pragma unroll
    for (int nt = 0; nt < 8; nt++) {
      const int br = (wn * 128 + nt * 16 + fr) * 32 + fqs;
      bhf[nt] = *(const v8s*)&base[16384 + br];
      blf[nt] = *(const v8s*)&base[24576 + br];
    }

    // --- 2) stage next buffer; flight time hides under the MFMAs below ---
    if (t < 15) stage((t + 1) & 1, (t + 1) * 32);

    // --- 3) MFMA cluster (compiler inserts counted lgkm waits per frag) ---
    #pragma unroll
    for (int nt = 0; nt < 8; nt++) {
      #pragma unroll
      for (int mt = 0; mt < 4; mt++) {
        acc[mt][nt] = MFMA16(ah[mt], bhf[nt], acc[mt][nt], 0, 0, 0);
        acc[mt][nt] = MFMA16(ah[mt], blf[nt], acc[mt][nt], 0, 0, 0);
        acc[mt][nt] = MFMA16(al[mt], bhf[nt], acc[mt][nt], 0, 0, 0);
      }
    }

    // --- 4) boundary: staging landed (had the whole MFMA phase) ---
    if (t < 15) __syncthreads();
  }

  // epilogue: C/D layout col=lane&15, row=(lane>>4)*4+reg
  const int col16 = lane & 15;
  float cn[8];
  #pragma unroll
  for (int nt = 0; nt < 8; nt++) cn[nt] = cnorm[c0 + wn * 128 + nt * 16 + col16];

  #pragma unroll
  for (int mt = 0; mt < 4; mt++) {
    #pragma unroll
    for (int reg = 0; reg < 4; reg++) {
      const int row = r0 + wm * 64 + mt * 16 + q * 4 + reg;
      float best = fmaf(-2.f, acc[mt][0][reg], cn[0]);
      int bid2 = c0 + wn * 128 + col16;
      #pragma unroll
      for (int nt = 1; nt < 8; nt++) {
        const float s = fmaf(-2.f, acc[mt][nt][reg], cn[nt]);
        const int id = c0 + wn * 128 + nt * 16 + col16;
        if (s < best) { best = s; bid2 = id; }
      }
      unsigned long long v =
          ((unsigned long long)f2ord(best) << 32) | (unsigned int)bid2;
      #pragma unroll
      for (int off = 8; off > 0; off >>= 1) {
        const unsigned long long o = __shfl_down(v, off, 16);
        if (o < v) v = o;
      }
      if (col16 == 0) atomicMin(&rowmin[row], v);
    }
  }
}

// ---------------------------------------------------------------------------
// Kernel 4: finalize — ids as float + gather q rows.
// ---------------------------------------------------------------------------
__global__ __launch_bounds__(64) void k_final(const unsigned long long* __restrict__ rowmin,
                                              const float* __restrict__ cb,
                                              float* __restrict__ out,
                                              int B) {
  const int b = blockIdx.x;
  const int t = threadIdx.x;
  const unsigned long long m = rowmin[b];
  const int id = (int)(unsigned int)(m & 0xFFFFFFFFull);
  if (t == 0) out[b] = (float)id;
  float4* q4 = (float4*)(out + B) + b * 128;
  const float4* cb4 = (const float4*)cb + (size_t)id * 128;
  q4[t] = cb4[t];
  q4[t + 64] = cb4[t + 64];
}

// ---------------------------------------------------------------------------
extern "C" void kernel_launch(void* const* d_in, const int* in_sizes, int n_in,
                              void* d_out, int out_size, void* d_ws, size_t ws_size,
                              hipStream_t stream) {
  const int* zt = (const int*)d_in[0];
  const int* ztp = (const int*)d_in[1];
  const float* emb = (const float*)d_in[2];
  const float* w1 = (const float*)d_in[3];
  const float* b1 = (const float*)d_in[4];
  const float* w2 = (const float*)d_in[5];
  const float* b2 = (const float*)d_in[6];
  const float* cb = (const float*)d_in[7];
  float* out = (float*)d_out;

  const int B = in_sizes[0] / TOK;        // 2048
  const int A = in_sizes[7] / DIMC;       // 16384

  char* p = (char*)d_ws;
  unsigned short* hh = (unsigned short*)p;  p += (size_t)B * 1024 * 2;
  unsigned short* hl = (unsigned short*)p;  p += (size_t)B * 1024 * 2;
  unsigned short* w1th = (unsigned short*)p; p += (size_t)512 * 1024 * 2;
  unsigned short* w1tl = (unsigned short*)p; p += (size_t)512 * 1024 * 2;
  unsigned short* w2th = (unsigned short*)p; p += (size_t)512 * 512 * 2;
  unsigned short* w2tl = (unsigned short*)p; p += (size_t)512 * 512 * 2;
  unsigned short* h1h = (unsigned short*)p; p += (size_t)B * DIMC * 2;
  unsigned short* h1l = (unsigned short*)p; p += (size_t)B * DIMC * 2;
  unsigned short* eh = (unsigned short*)p;  p += (size_t)B * DIMC * 2;
  unsigned short* el = (unsigned short*)p;  p += (size_t)B * DIMC * 2;
  unsigned short* ch = (unsigned short*)p;  p += (size_t)A * DIMC * 2;
  unsigned short* cl = (unsigned short*)p;  p += (size_t)A * DIMC * 2;
  float* cnorm = (float*)p;                 p += (size_t)A * 4;
  unsigned long long* rowmin = (unsigned long long*)p;

  k_prep<<<2816 + A / 4, 256, 0, stream>>>(zt, ztp, emb, hh, hl, rowmin,
                                           w1, w1th, w1tl, w2, w2th, w2tl,
                                           cb, ch, cl, cnorm);
  k_gemm<true><<<dim3(B / 32, 512 / 64), 256, 0, stream>>>(hh, hl, w1th, w1tl, b1, h1h, h1l, 1024, 512);
  k_gemm<false><<<dim3(B / 32, 512 / 64), 256, 0, stream>>>(h1h, h1l, w2th, w2tl, b2, eh, el, 512, 512);
  k_vq<<<(B / 256) * (A / 256), 512, 0, stream>>>(eh, el, ch, cl, cnorm, rowmin);
  k_final<<<B, 64, 0, stream>>>(rowmin, cb, out, B);
}

// Round 9
// 222.025 us; speedup vs baseline: 1.0562x; 1.0063x over previous
//
#include <hip/hip_runtime.h>
#include <hip/hip_bf16.h>

#define TOK 64
#define DIMC 512

typedef __attribute__((ext_vector_type(8))) short v8s;   // 8 bf16 = 4 VGPRs
typedef __attribute__((ext_vector_type(4))) float v4f;   // MFMA 16x16 acc

#define MFMA16 __builtin_amdgcn_mfma_f32_16x16x32_bf16

__device__ __forceinline__ unsigned int f2ord(float f) {
  unsigned int u = __float_as_uint(f);
  return (u & 0x80000000u) ? ~u : (u | 0x80000000u);
}

__device__ __forceinline__ float gelu_exact(float x) {
  return 0.5f * x * (1.0f + erff(x * 0.70710678118654752440f));
}

__device__ __forceinline__ unsigned short f2bf(float x) {  // RNE
  unsigned int u = __float_as_uint(x);
  return (unsigned short)((u + 0x7FFFu + ((u >> 16) & 1u)) >> 16);
}
__device__ __forceinline__ float bf2f(unsigned short h) {
  return __uint_as_float((unsigned int)h << 16);
}

__device__ __forceinline__ void gl2lds16(const void* g, void* l) {
  __builtin_amdgcn_global_load_lds((const __attribute__((address_space(1))) void*)g,
                                   (__attribute__((address_space(3))) void*)l,
                                   16, 0, 0);
}

// ---------------------------------------------------------------------------
// Kernel 1: fused prep. Roles by blockIdx.x:
//   [0,2048)      embed+pool -> hh/hl, init rowmin
//   [2048,2560)   w1 transpose+split
//   [2560,2816)   w2 transpose+split
//   [2816,6912)   codebook split + norms
// ---------------------------------------------------------------------------
__global__ __launch_bounds__(256) void k_prep(
    const int* __restrict__ zt, const int* __restrict__ ztp,
    const float* __restrict__ emb,
    unsigned short* __restrict__ hh, unsigned short* __restrict__ hl,
    unsigned long long* __restrict__ rowmin,
    const float* __restrict__ w1, unsigned short* __restrict__ w1th,
    unsigned short* __restrict__ w1tl,
    const float* __restrict__ w2, unsigned short* __restrict__ w2th,
    unsigned short* __restrict__ w2tl,
    const float* __restrict__ cb, unsigned short* __restrict__ ch,
    unsigned short* __restrict__ cl, float* __restrict__ cnorm) {
  __shared__ int codes[128];
  __shared__ float tbuf[32][33];
  const int bid = blockIdx.x;
  const int tid = threadIdx.x;

  if (bid < 2048) {
    // ---- embed + mean-pool ----
    const int b = bid;
    if (tid < 64) codes[tid] = zt[b * TOK + tid];
    else if (tid < 128) codes[tid] = ztp[b * TOK + (tid - 64)];
    if (tid == 0) rowmin[b] = 0xFFFFFFFFFFFFFFFFull;
    __syncthreads();
    const int half = tid >> 7;
    const int c4 = tid & 127;
    const float4* emb4 = (const float4*)emb;
    float4 s = make_float4(0.f, 0.f, 0.f, 0.f);
    #pragma unroll 8
    for (int t = 0; t < TOK; t++) {
      const int code = codes[half * TOK + t];
      const float4 v = emb4[code * 128 + c4];
      s.x += v.x; s.y += v.y; s.z += v.z; s.w += v.w;
    }
    const float inv = 1.0f / 64.0f;
    float f[4] = {s.x * inv, s.y * inv, s.z * inv, s.w * inv};
    unsigned short hi[4], lo[4];
    #pragma unroll
    for (int i = 0; i < 4; i++) {
      hi[i] = f2bf(f[i]);
      lo[i] = f2bf(f[i] - bf2f(hi[i]));
    }
    const int off = b * 1024 + half * 512 + c4 * 4;
    *(ushort4*)&hh[off] = make_ushort4(hi[0], hi[1], hi[2], hi[3]);
    *(ushort4*)&hl[off] = make_ushort4(lo[0], lo[1], lo[2], lo[3]);
  } else if (bid < 2816) {
    // ---- weight transpose + split ----
    const float* w; unsigned short *wth, *wtl; int Kd, N, k0, n0;
    if (bid < 2560) {
      const int i = bid - 2048;
      w = w1; wth = w1th; wtl = w1tl; Kd = 1024; N = 512;
      k0 = (i & 31) * 32; n0 = (i >> 5) * 32;
    } else {
      const int i = bid - 2560;
      w = w2; wth = w2th; wtl = w2tl; Kd = 512; N = 512;
      k0 = (i & 15) * 32; n0 = (i >> 4) * 32;
    }
    const int c = tid & 31, r = tid >> 5;  // r: 0..7
    #pragma unroll
    for (int i = 0; i < 4; i++)
      tbuf[r + i * 8][c] = w[(size_t)(k0 + r + i * 8) * N + n0 + c];
    __syncthreads();
    #pragma unroll
    for (int i = 0; i < 4; i++) {
      const float v = tbuf[c][r + i * 8];
      const unsigned short hi = f2bf(v);
      const unsigned short lo = f2bf(v - bf2f(hi));
      wth[(size_t)(n0 + r + i * 8) * Kd + k0 + c] = hi;
      wtl[(size_t)(n0 + r + i * 8) * Kd + k0 + c] = lo;
    }
  } else {
    // ---- codebook split + norms (one wave per row) ----
    const int row = (bid - 2816) * 4 + (tid >> 6);
    const int lane = tid & 63;
    const float4* cb4 = (const float4*)cb;
    const float4 va = cb4[row * 128 + lane * 2];
    const float4 vb = cb4[row * 128 + lane * 2 + 1];
    float s = va.x * va.x + va.y * va.y + va.z * va.z + va.w * va.w
            + vb.x * vb.x + vb.y * vb.y + vb.z * vb.z + vb.w * vb.w;
    float f[8] = {va.x, va.y, va.z, va.w, vb.x, vb.y, vb.z, vb.w};
    unsigned short hi[8], lo[8];
    #pragma unroll
    for (int i = 0; i < 8; i++) {
      hi[i] = f2bf(f[i]);
      lo[i] = f2bf(f[i] - bf2f(hi[i]));
    }
    ushort4* chp = (ushort4*)&ch[row * DIMC + lane * 8];
    ushort4* clp = (ushort4*)&cl[row * DIMC + lane * 8];
    chp[0] = make_ushort4(hi[0], hi[1], hi[2], hi[3]);
    chp[1] = make_ushort4(hi[4], hi[5], hi[6], hi[7]);
    clp[0] = make_ushort4(lo[0], lo[1], lo[2], lo[3]);
    clp[1] = make_ushort4(lo[4], lo[5], lo[6], lo[7]);
    #pragma unroll
    for (int off = 32; off > 0; off >>= 1) s += __shfl_down(s, off);
    if (lane == 0) cnorm[row] = s;
  }
}

// ---------------------------------------------------------------------------
// Kernel 2: split-bf16 MFMA GEMM, BK=64 as TWO 32-k slabs per LDS step.
// R7 post-mortem: gemms are step-latency-bound (full barrier+vmcnt drain per
// K-step, only 12 MFMAs/wave/step); halving the step count (32->16 for K=1024,
// 16->8 for K=512) halves the fixed per-step cost. Slab layout keeps the
// verified conflict-free quad-swizzle pattern (R5: conflicts 0) per slab:
//   staging source col swizzle: (lane&3)^((lane>>3)&3), read: q^((fr>>1)&3).
// Per-acc accumulation remains k-subtile-sequential (kk=0 then kk=1, each
// hh,hl,lh) -> bitwise-identical to the BK=32 version.
// LDS 48 KB dbuf -> 2-3 blocks/CU at 256 thr; grid 512 = 2/CU.
// ---------------------------------------------------------------------------
template <bool GELU>
__global__ __launch_bounds__(256) void k_gemm(const unsigned short* __restrict__ Ah_,
                                              const unsigned short* __restrict__ Al_,
                                              const unsigned short* __restrict__ Bh_,
                                              const unsigned short* __restrict__ Bl_,
                                              const float* __restrict__ bias,
                                              unsigned short* __restrict__ oh,
                                              unsigned short* __restrict__ ol,
                                              int Kd, int N) {
  // per buffer: [slab][row][32] — A: 2x32x32, B: 2x64x32 shorts
  __shared__ unsigned short AhS[2][2048];   // 4 KB per buf
  __shared__ unsigned short AlS[2][2048];
  __shared__ unsigned short BhS[2][4096];   // 8 KB per buf
  __shared__ unsigned short BlS[2][4096];

  const int tid = threadIdx.x;
  const int lane = tid & 63;
  const int wid = tid >> 6;
  const int m0 = blockIdx.x * 32;
  const int n0 = blockIdx.y * 64;

  const unsigned short* Ab_h = Ah_ + (size_t)m0 * Kd;
  const unsigned short* Ab_l = Al_ + (size_t)m0 * Kd;
  const unsigned short* Bb_h = Bh_ + (size_t)n0 * Kd;
  const unsigned short* Bb_l = Bl_ + (size_t)n0 * Kd;

  const int srow = lane >> 2;         // 0..15
  const int sk = ((lane & 3) ^ ((lane >> 3) & 3)) * 8;   // swizzled src col (shorts)
  const int wm = wid >> 1, wn = wid & 1;
  const int fr = lane & 15;
  const int q = lane >> 4;
  const int fqs = (q ^ ((fr >> 1) & 3)) * 8;             // swizzled read col

  v4f acc[2];
  acc[0] = (v4f)(0.f);
  acc[1] = (v4f)(0.f);

  // stage one 64-k slice (24 issues, 6 per wave): 2 slabs x {Ah:2,Al:2,Bh:4,Bl:4}
  auto stage = [&](int b, int k0) {
    #pragma unroll
    for (int u = 0; u < 6; u++) {
      const int i = wid * 6 + u;   // wave-uniform, 0..23
      const unsigned short* gs; unsigned short* ls; int slab, seg, rstride;
      if (i < 4)       { gs = Ab_h; ls = AhS[b]; slab = i >> 1;         seg = i & 1;         rstride = 1024; }
      else if (i < 8)  { gs = Ab_l; ls = AlS[b]; slab = (i - 4) >> 1;   seg = (i - 4) & 1;   rstride = 1024; }
      else if (i < 16) { gs = Bb_h; ls = BhS[b]; slab = (i - 8) >> 2;   seg = (i - 8) & 3;   rstride = 2048; }
      else             { gs = Bb_l; ls = BlS[b]; slab = (i - 16) >> 2;  seg = (i - 16) & 3;  rstride = 2048; }
      gl2lds16(gs + (size_t)(seg * 16 + srow) * Kd + k0 + slab * 32 + sk,
               ls + slab * rstride + seg * 512);
    }
  };

  stage(0, 0);
  int cur = 0;
  for (int k0 = 0; k0 < Kd; k0 += 64) {
    __syncthreads();               // drains vmcnt -> buf `cur` ready
    if (k0 + 64 < Kd) stage(cur ^ 1, k0 + 64);  // in flight during compute

    #pragma unroll
    for (int kk = 0; kk < 2; kk++) {
      const int ar = kk * 1024 + (wm * 16 + fr) * 32 + fqs;
      const v8s ah = *(const v8s*)&AhS[cur][ar];
      const v8s al = *(const v8s*)&AlS[cur][ar];
      #pragma unroll
      for (int nt = 0; nt < 2; nt++) {
        const int br = kk * 2048 + (wn * 32 + nt * 16 + fr) * 32 + fqs;
        const v8s bh = *(const v8s*)&BhS[cur][br];
        const v8s bl = *(const v8s*)&BlS[cur][br];
        acc[nt] = MFMA16(ah, bh, acc[nt], 0, 0, 0);
        acc[nt] = MFMA16(ah, bl, acc[nt], 0, 0, 0);
        acc[nt] = MFMA16(al, bh, acc[nt], 0, 0, 0);
      }
    }
    cur ^= 1;
  }

  // epilogue: C/D layout col=lane&15, row=(lane>>4)*4+reg
  const int col16 = lane & 15;
  #pragma unroll
  for (int nt = 0; nt < 2; nt++) {
    const int col = n0 + wn * 32 + nt * 16 + col16;
    const float bv = bias[col];
    #pragma unroll
    for (int reg = 0; reg < 4; reg++) {
      const int row = m0 + wm * 16 + q * 4 + reg;
      float v = acc[nt][reg] + bv;
      if (GELU) v = gelu_exact(v);
      const unsigned short hi = f2bf(v);
      oh[(size_t)row * N + col] = hi;
      ol[(size_t)row * N + col] = f2bf(v - bf2f(hi));
    }
  }
}

// ---------------------------------------------------------------------------
// Kernel 3: VQ via split-bf16 MFMA GEMM — R5 EXACT (best measured: 91.3 µs,
// MfmaUtil 49%, SQ_LDS_BANK_CONFLICT 0). 2-phase issue-early double-buffer,
// 256x256 tile, 512 thr = 8 waves 4M x 2N, wave tile 64x128, BK=32,
// conflict-free quad-swizzle. DECLARED STRUCTURAL FLOOR for this session:
// beaten variants = 3-buf counted-vmcnt (117), 4-phase (98), 32x32 shape
// (121), 16-wave (101), reads-first clustering (104). Do not touch.
// score = ||c||^2 - 2*e.c
// ---------------------------------------------------------------------------
__global__ __launch_bounds__(512, 2) void k_vq(const unsigned short* __restrict__ eh,
                                               const unsigned short* __restrict__ el,
                                               const unsigned short* __restrict__ ch,
                                               const unsigned short* __restrict__ cl,
                                               const float* __restrict__ cnorm,
                                               unsigned long long* __restrict__ rowmin) {
  // per buffer (shorts): Ah[256*32] | Al[256*32] | Bh[256*32] | Bl[256*32]
  __shared__ unsigned short lds[2 * 32768];   // 128 KB

  const int tid = threadIdx.x;
  const int lane = tid & 63;
  const int wid = tid >> 6;                  // 0..7
  const int bid = blockIdx.x;
  const int x = (bid >> 3) & 7;              // 8 e-tiles (256 rows)
  const int y = (((bid >> 6) & 7) << 3) | (bid & 7);  // 64 cb-tiles (256 rows)
  const int r0 = x * 256;
  const int c0 = y * 256;

  const unsigned short* ehB = eh + (size_t)r0 * DIMC;
  const unsigned short* elB = el + (size_t)r0 * DIMC;
  const unsigned short* chB = ch + (size_t)c0 * DIMC;
  const unsigned short* clB = cl + (size_t)c0 * DIMC;

  const int srow = lane >> 2;                // 0..15
  // staging source quad swizzle: physical quad (lane&3) holds logical quad
  // (lane&3) ^ ((srow>>1)&3) = (lane&3) ^ ((lane>>3)&3)
  const int sk = ((lane & 3) ^ ((lane >> 3) & 3)) * 8;   // shorts
  const int wm = wid >> 1;                   // 0..3 (M)
  const int wn = wid & 1;                    // 0..1 (N)
  const int fr = lane & 15;
  const int q = lane >> 4;
  // fragment read quad swizzle: logical quad q of row (...+fr) lives at
  // physical quad q ^ ((fr>>1)&3)  (row-base terms are multiples of 16)
  const int fqs = (q ^ ((fr >> 1) & 3)) * 8;

  v4f acc[4][8];
  #pragma unroll
  for (int i = 0; i < 4; i++)
    #pragma unroll
    for (int jj = 0; jj < 8; jj++) acc[i][jj] = (v4f)(0.f);

  // 64 staging segments of 16 rows each: 8 per wave (wave-uniform i)
  const unsigned short* gp[8];
  int lo_[8];
  #pragma unroll
  for (int u = 0; u < 8; u++) {
    const int i = wid * 8 + u;
    const unsigned short* gs; int off, rbase;
    if (i < 16)      { gs = ehB; off = 0;     rbase = i * 16; }
    else if (i < 32) { gs = elB; off = 8192;  rbase = (i - 16) * 16; }
    else if (i < 48) { gs = chB; off = 16384; rbase = (i - 32) * 16; }
    else             { gs = clB; off = 24576; rbase = (i - 48) * 16; }
    gp[u] = gs + (size_t)(rbase + srow) * DIMC + sk;
    lo_[u] = off + rbase * 32;   // wave-uniform LDS short-offset (linear dest)
  }

  auto stage = [&](int buf, int k0) {   // 8 x global_load_lds dwordx4 per wave
    #pragma unroll
    for (int u = 0; u < 8; u++)
      gl2lds16(gp[u] + k0, lds + buf * 32768 + lo_[u]);
  };

  stage(0, 0);
  __syncthreads();                       // buf0 landed

  for (int t = 0; t < 16; ++t) {         // 16 = DIMC/32 K-steps
    if (t < 15) stage((t + 1) & 1, (t + 1) * 32);  // issue early; hides under compute

    const unsigned short* base = lds + (t & 1) * 32768;
    v8s ah[4], al[4];
    #pragma unroll
    for (int mt = 0; mt < 4; mt++) {
      const int ar = (wm * 64 + mt * 16 + fr) * 32 + fqs;
      ah[mt] = *(const v8s*)&base[ar];
      al[mt] = *(const v8s*)&base[8192 + ar];
    }
    __builtin_amdgcn_s_setprio(1);
    #pragma unroll
    for (int nt = 0; nt < 8; nt++) {
      const int br = (wn * 128 + nt * 16 + fr) * 32 + fqs;
      const v8s bh = *(const v8s*)&base[16384 + br];
      const v8s bl = *(const v8s*)&base[24576 + br];
      #pragma unroll
      for (int mt = 0; mt < 4; mt++) {
        acc[mt][nt] = MFMA16(ah[mt], bh, acc[mt][nt], 0, 0, 0);
        acc[mt][nt] = MFMA16(ah[mt], bl, acc[mt][nt], 0, 0, 0);
        acc[mt][nt] = MFMA16(al[mt], bh, acc[mt][nt], 0, 0, 0);
      }
    }
    __builtin_amdgcn_s_setprio(0);
    if (t < 15) __syncthreads();         // drains vmcnt -> next buf ready
  }

  // epilogue: C/D layout col=lane&15, row=(lane>>4)*4+reg
  const int col16 = lane & 15;
  float cn[8];
  #pragma unroll
  for (int nt = 0; nt < 8; nt++) cn[nt] = cnorm[c0 + wn * 128 + nt * 16 + col16];

  #pragma unroll
  for (int mt = 0; mt < 4; mt++) {
    #pragma unroll
    for (int reg = 0; reg < 4; reg++) {
      const int row = r0 + wm * 64 + mt * 16 + q * 4 + reg;
      float best = fmaf(-2.f, acc[mt][0][reg], cn[0]);
      int bid2 = c0 + wn * 128 + col16;
      #pragma unroll
      for (int nt = 1; nt < 8; nt++) {
        const float s = fmaf(-2.f, acc[mt][nt][reg], cn[nt]);
        const int id = c0 + wn * 128 + nt * 16 + col16;
        if (s < best) { best = s; bid2 = id; }
      }
      unsigned long long v =
          ((unsigned long long)f2ord(best) << 32) | (unsigned int)bid2;
      #pragma unroll
      for (int off = 8; off > 0; off >>= 1) {
        const unsigned long long o = __shfl_down(v, off, 16);
        if (o < v) v = o;
      }
      if (col16 == 0) atomicMin(&rowmin[row], v);
    }
  }
}

// ---------------------------------------------------------------------------
// Kernel 4: finalize — ids as float + gather q rows.
// ---------------------------------------------------------------------------
__global__ __launch_bounds__(64) void k_final(const unsigned long long* __restrict__ rowmin,
                                              const float* __restrict__ cb,
                                              float* __restrict__ out,
                                              int B) {
  const int b = blockIdx.x;
  const int t = threadIdx.x;
  const unsigned long long m = rowmin[b];
  const int id = (int)(unsigned int)(m & 0xFFFFFFFFull);
  if (t == 0) out[b] = (float)id;
  float4* q4 = (float4*)(out + B) + b * 128;
  const float4* cb4 = (const float4*)cb + (size_t)id * 128;
  q4[t] = cb4[t];
  q4[t + 64] = cb4[t + 64];
}

// ---------------------------------------------------------------------------
extern "C" void kernel_launch(void* const* d_in, const int* in_sizes, int n_in,
                              void* d_out, int out_size, void* d_ws, size_t ws_size,
                              hipStream_t stream) {
  const int* zt = (const int*)d_in[0];
  const int* ztp = (const int*)d_in[1];
  const float* emb = (const float*)d_in[2];
  const float* w1 = (const float*)d_in[3];
  const float* b1 = (const float*)d_in[4];
  const float* w2 = (const float*)d_in[5];
  const float* b2 = (const float*)d_in[6];
  const float* cb = (const float*)d_in[7];
  float* out = (float*)d_out;

  const int B = in_sizes[0] / TOK;        // 2048
  const int A = in_sizes[7] / DIMC;       // 16384

  char* p = (char*)d_ws;
  unsigned short* hh = (unsigned short*)p;  p += (size_t)B * 1024 * 2;
  unsigned short* hl = (unsigned short*)p;  p += (size_t)B * 1024 * 2;
  unsigned short* w1th = (unsigned short*)p; p += (size_t)512 * 1024 * 2;
  unsigned short* w1tl = (unsigned short*)p; p += (size_t)512 * 1024 * 2;
  unsigned short* w2th = (unsigned short*)p; p += (size_t)512 * 512 * 2;
  unsigned short* w2tl = (unsigned short*)p; p += (size_t)512 * 512 * 2;
  unsigned short* h1h = (unsigned short*)p; p += (size_t)B * DIMC * 2;
  unsigned short* h1l = (unsigned short*)p; p += (size_t)B * DIMC * 2;
  unsigned short* eh = (unsigned short*)p;  p += (size_t)B * DIMC * 2;
  unsigned short* el = (unsigned short*)p;  p += (size_t)B * DIMC * 2;
  unsigned short* ch = (unsigned short*)p;  p += (size_t)A * DIMC * 2;
  unsigned short* cl = (unsigned short*)p;  p += (size_t)A * DIMC * 2;
  float* cnorm = (float*)p;                 p += (size_t)A * 4;
  unsigned long long* rowmin = (unsigned long long*)p;

  k_prep<<<2816 + A / 4, 256, 0, stream>>>(zt, ztp, emb, hh, hl, rowmin,
                                           w1, w1th, w1tl, w2, w2th, w2tl,
                                           cb, ch, cl, cnorm);
  k_gemm<true><<<dim3(B / 32, 512 / 64), 256, 0, stream>>>(hh, hl, w1th, w1tl, b1, h1h, h1l, 1024, 512);
  k_gemm<false><<<dim3(B / 32, 512 / 64), 256, 0, stream>>>(h1h, h1l, w2th, w2tl, b2, eh, el, 512, 512);
  k_vq<<<(B / 256) * (A / 256), 512, 0, stream>>>(eh, el, ch, cl, cnorm, rowmin);
  k_final<<<B, 64, 0, stream>>>(rowmin, cb, out, B);
}

// Round 10
// 216.627 us; speedup vs baseline: 1.0826x; 1.0249x over previous
//
#include <hip/hip_runtime.h>
#include <hip/hip_bf16.h>

#define TOK 64
#define DIMC 512

typedef __attribute__((ext_vector_type(8))) short v8s;   // 8 bf16 = 4 VGPRs
typedef __attribute__((ext_vector_type(4))) float v4f;   // MFMA 16x16 acc

#define MFMA16 __builtin_amdgcn_mfma_f32_16x16x32_bf16

__device__ __forceinline__ unsigned int f2ord(float f) {
  unsigned int u = __float_as_uint(f);
  return (u & 0x80000000u) ? ~u : (u | 0x80000000u);
}

__device__ __forceinline__ float gelu_exact(float x) {
  return 0.5f * x * (1.0f + erff(x * 0.70710678118654752440f));
}

__device__ __forceinline__ unsigned short f2bf(float x) {  // RNE
  unsigned int u = __float_as_uint(x);
  return (unsigned short)((u + 0x7FFFu + ((u >> 16) & 1u)) >> 16);
}
__device__ __forceinline__ float bf2f(unsigned short h) {
  return __uint_as_float((unsigned int)h << 16);
}

__device__ __forceinline__ void gl2lds16(const void* g, void* l) {
  __builtin_amdgcn_global_load_lds((const __attribute__((address_space(1))) void*)g,
                                   (__attribute__((address_space(3))) void*)l,
                                   16, 0, 0);
}

// ---------------------------------------------------------------------------
// Kernel 1: prep for gemm1 ONLY (R9 post-mortem: cb-split and w2t don't gate
// gemm1 — moved into the gemm1 launch to overlap with its compute).
// Roles: [0,2048) embed+pool -> hh/hl + rowmin init; [2048,2560) w1 t+split.
// ---------------------------------------------------------------------------
__global__ __launch_bounds__(256) void k_prep(
    const int* __restrict__ zt, const int* __restrict__ ztp,
    const float* __restrict__ emb,
    unsigned short* __restrict__ hh, unsigned short* __restrict__ hl,
    unsigned long long* __restrict__ rowmin,
    const float* __restrict__ w1, unsigned short* __restrict__ w1th,
    unsigned short* __restrict__ w1tl) {
  __shared__ int codes[128];
  __shared__ float tbuf[32][33];
  const int bid = blockIdx.x;
  const int tid = threadIdx.x;

  if (bid < 2048) {
    // ---- embed + mean-pool ----
    const int b = bid;
    if (tid < 64) codes[tid] = zt[b * TOK + tid];
    else if (tid < 128) codes[tid] = ztp[b * TOK + (tid - 64)];
    if (tid == 0) rowmin[b] = 0xFFFFFFFFFFFFFFFFull;
    __syncthreads();
    const int half = tid >> 7;
    const int c4 = tid & 127;
    const float4* emb4 = (const float4*)emb;
    float4 s = make_float4(0.f, 0.f, 0.f, 0.f);
    #pragma unroll 8
    for (int t = 0; t < TOK; t++) {
      const int code = codes[half * TOK + t];
      const float4 v = emb4[code * 128 + c4];
      s.x += v.x; s.y += v.y; s.z += v.z; s.w += v.w;
    }
    const float inv = 1.0f / 64.0f;
    float f[4] = {s.x * inv, s.y * inv, s.z * inv, s.w * inv};
    unsigned short hi[4], lo[4];
    #pragma unroll
    for (int i = 0; i < 4; i++) {
      hi[i] = f2bf(f[i]);
      lo[i] = f2bf(f[i] - bf2f(hi[i]));
    }
    const int off = b * 1024 + half * 512 + c4 * 4;
    *(ushort4*)&hh[off] = make_ushort4(hi[0], hi[1], hi[2], hi[3]);
    *(ushort4*)&hl[off] = make_ushort4(lo[0], lo[1], lo[2], lo[3]);
  } else {
    // ---- w1 transpose + split ----
    const int i = bid - 2048;
    const int Kd = 1024, N = 512;
    const int k0 = (i & 31) * 32, n0 = (i >> 5) * 32;
    const int c = tid & 31, r = tid >> 5;  // r: 0..7
    #pragma unroll
    for (int j = 0; j < 4; j++)
      tbuf[r + j * 8][c] = w1[(size_t)(k0 + r + j * 8) * N + n0 + c];
    __syncthreads();
    #pragma unroll
    for (int j = 0; j < 4; j++) {
      const float v = tbuf[c][r + j * 8];
      const unsigned short hi = f2bf(v);
      const unsigned short lo = f2bf(v - bf2f(hi));
      w1th[(size_t)(n0 + r + j * 8) * Kd + k0 + c] = hi;
      w1tl[(size_t)(n0 + r + j * 8) * Kd + k0 + c] = lo;
    }
  }
}

// ---------------------------------------------------------------------------
// Kernel 2a: FUSED launch — gemm1 (GELU) + w2 transpose + codebook split.
// Role-split by blockIdx.x: [0,512) gemm1 32x64 tiles (BK=64, two 32-k slabs,
// verified quad-swizzle, bit-identical accumulation); [512,768) w2 t+split
// (consumed by gemm2, next launch); [768,4864) codebook split + norms
// (consumed by k_vq, later launch). The ~15 µs of cb-split BW work now runs
// concurrently with gemm1 compute on other CUs instead of serially before it.
// Shared-memory union: 48 KB gemm buffers / 4.2 KB float tbuf alias.
// ---------------------------------------------------------------------------
__global__ __launch_bounds__(256) void k_gemm1_fused(
    const unsigned short* __restrict__ Ah_, const unsigned short* __restrict__ Al_,
    const unsigned short* __restrict__ Bh_, const unsigned short* __restrict__ Bl_,
    const float* __restrict__ bias,
    unsigned short* __restrict__ oh, unsigned short* __restrict__ ol,
    const float* __restrict__ w2, unsigned short* __restrict__ w2th,
    unsigned short* __restrict__ w2tl,
    const float* __restrict__ cb, unsigned short* __restrict__ ch,
    unsigned short* __restrict__ cl, float* __restrict__ cnorm) {
  __shared__ unsigned short smem[24576];   // 48 KB union
  const int bid = blockIdx.x;
  const int tid = threadIdx.x;

  if (bid < 512) {
    // ---- gemm1: h1 = gelu(h @ w1 + b1), split-bf16, Kd=1024, N=512 ----
    const int Kd = 1024, N = 512;
    const int lane = tid & 63;
    const int wid = tid >> 6;
    const int m0 = (bid & 63) * 32;
    const int n0 = (bid >> 6) * 64;

    const unsigned short* Ab_h = Ah_ + (size_t)m0 * Kd;
    const unsigned short* Ab_l = Al_ + (size_t)m0 * Kd;
    const unsigned short* Bb_h = Bh_ + (size_t)n0 * Kd;
    const unsigned short* Bb_l = Bl_ + (size_t)n0 * Kd;

    const int srow = lane >> 2;
    const int sk = ((lane & 3) ^ ((lane >> 3) & 3)) * 8;   // swizzled src col
    const int wm = wid >> 1, wn = wid & 1;
    const int fr = lane & 15;
    const int q = lane >> 4;
    const int fqs = (q ^ ((fr >> 1) & 3)) * 8;             // swizzled read col

    v4f acc[2];
    acc[0] = (v4f)(0.f);
    acc[1] = (v4f)(0.f);

    // smem layout (shorts): Ah[2][2048] | Al[2][2048] | Bh[2][4096] | Bl[2][4096]
    auto stage = [&](int b, int k0) {
      #pragma unroll
      for (int u = 0; u < 6; u++) {
        const int i = wid * 6 + u;   // wave-uniform, 0..23
        const unsigned short* gs; unsigned short* ls; int slab, seg, rstride;
        if (i < 4)       { gs = Ab_h; ls = smem + b * 2048;          slab = i >> 1;        seg = i & 1;        rstride = 1024; }
        else if (i < 8)  { gs = Ab_l; ls = smem + 4096 + b * 2048;   slab = (i - 4) >> 1;  seg = (i - 4) & 1;  rstride = 1024; }
        else if (i < 16) { gs = Bb_h; ls = smem + 8192 + b * 4096;   slab = (i - 8) >> 2;  seg = (i - 8) & 3;  rstride = 2048; }
        else             { gs = Bb_l; ls = smem + 16384 + b * 4096;  slab = (i - 16) >> 2; seg = (i - 16) & 3; rstride = 2048; }
        gl2lds16(gs + (size_t)(seg * 16 + srow) * Kd + k0 + slab * 32 + sk,
                 ls + slab * rstride + seg * 512);
      }
    };

    stage(0, 0);
    int cur = 0;
    for (int k0 = 0; k0 < Kd; k0 += 64) {
      __syncthreads();
      if (k0 + 64 < Kd) stage(cur ^ 1, k0 + 64);

      #pragma unroll
      for (int kk = 0; kk < 2; kk++) {
        const int ar = kk * 1024 + (wm * 16 + fr) * 32 + fqs;
        const v8s ah = *(const v8s*)&smem[cur * 2048 + ar];
        const v8s al = *(const v8s*)&smem[4096 + cur * 2048 + ar];
        #pragma unroll
        for (int nt = 0; nt < 2; nt++) {
          const int br = kk * 2048 + (wn * 32 + nt * 16 + fr) * 32 + fqs;
          const v8s bh = *(const v8s*)&smem[8192 + cur * 4096 + br];
          const v8s bl = *(const v8s*)&smem[16384 + cur * 4096 + br];
          acc[nt] = MFMA16(ah, bh, acc[nt], 0, 0, 0);
          acc[nt] = MFMA16(ah, bl, acc[nt], 0, 0, 0);
          acc[nt] = MFMA16(al, bh, acc[nt], 0, 0, 0);
        }
      }
      cur ^= 1;
    }

    const int col16 = lane & 15;
    #pragma unroll
    for (int nt = 0; nt < 2; nt++) {
      const int col = n0 + wn * 32 + nt * 16 + col16;
      const float bv = bias[col];
      #pragma unroll
      for (int reg = 0; reg < 4; reg++) {
        const int row = m0 + wm * 16 + q * 4 + reg;
        float v = acc[nt][reg] + bv;
        v = gelu_exact(v);
        const unsigned short hi = f2bf(v);
        oh[(size_t)row * N + col] = hi;
        ol[(size_t)row * N + col] = f2bf(v - bf2f(hi));
      }
    }
  } else if (bid < 768) {
    // ---- w2 transpose + split (Kd=512, N=512) ----
    const int i = bid - 512;
    const int k0 = (i & 15) * 32, n0 = (i >> 4) * 32;
    float* tbuf = (float*)smem;   // [32][33] alias
    const int c = tid & 31, r = tid >> 5;
    #pragma unroll
    for (int j = 0; j < 4; j++)
      tbuf[(r + j * 8) * 33 + c] = w2[(size_t)(k0 + r + j * 8) * 512 + n0 + c];
    __syncthreads();
    #pragma unroll
    for (int j = 0; j < 4; j++) {
      const float v = tbuf[c * 33 + r + j * 8];
      const unsigned short hi = f2bf(v);
      const unsigned short lo = f2bf(v - bf2f(hi));
      w2th[(size_t)(n0 + r + j * 8) * 512 + k0 + c] = hi;
      w2tl[(size_t)(n0 + r + j * 8) * 512 + k0 + c] = lo;
    }
  } else {
    // ---- codebook split + norms (one wave per row) ----
    const int row = (bid - 768) * 4 + (tid >> 6);
    const int lane = tid & 63;
    const float4* cb4 = (const float4*)cb;
    const float4 va = cb4[row * 128 + lane * 2];
    const float4 vb = cb4[row * 128 + lane * 2 + 1];
    float s = va.x * va.x + va.y * va.y + va.z * va.z + va.w * va.w
            + vb.x * vb.x + vb.y * vb.y + vb.z * vb.z + vb.w * vb.w;
    float f[8] = {va.x, va.y, va.z, va.w, vb.x, vb.y, vb.z, vb.w};
    unsigned short hi[8], lo[8];
    #pragma unroll
    for (int i = 0; i < 8; i++) {
      hi[i] = f2bf(f[i]);
      lo[i] = f2bf(f[i] - bf2f(hi[i]));
    }
    ushort4* chp = (ushort4*)&ch[row * DIMC + lane * 8];
    ushort4* clp = (ushort4*)&cl[row * DIMC + lane * 8];
    chp[0] = make_ushort4(hi[0], hi[1], hi[2], hi[3]);
    chp[1] = make_ushort4(hi[4], hi[5], hi[6], hi[7]);
    clp[0] = make_ushort4(lo[0], lo[1], lo[2], lo[3]);
    clp[1] = make_ushort4(lo[4], lo[5], lo[6], lo[7]);
    #pragma unroll
    for (int off = 32; off > 0; off >>= 1) s += __shfl_down(s, off);
    if (lane == 0) cnorm[row] = s;
  }
}

// ---------------------------------------------------------------------------
// Kernel 2b: gemm2 (no GELU), BK=64 two-slab, same structure as gemm1 role.
// ---------------------------------------------------------------------------
__global__ __launch_bounds__(256) void k_gemm2(const unsigned short* __restrict__ Ah_,
                                               const unsigned short* __restrict__ Al_,
                                               const unsigned short* __restrict__ Bh_,
                                               const unsigned short* __restrict__ Bl_,
                                               const float* __restrict__ bias,
                                               unsigned short* __restrict__ oh,
                                               unsigned short* __restrict__ ol) {
  __shared__ unsigned short AhS[2][1024];   // 2 slabs x 32 rows x 32 shorts / 2... [slab-major packed]
  __shared__ unsigned short AlS[2][1024];
  __shared__ unsigned short BhS[2][2048];
  __shared__ unsigned short BlS[2][2048];
  // NOTE: Kd=512 -> BK=64 means 8 steps; A slab = 32x32 shorts = 1024? A is
  // 32 rows x 32 k-shorts = 1024 shorts per slab, 2 slabs = 2048. Sizes below
  // use explicit [2][2048]/[2][4096] layout identical to gemm1.
  (void)AhS; (void)AlS; (void)BhS; (void)BlS;
  __shared__ unsigned short smem[24576];

  const int Kd = 512, N = 512;
  const int tid = threadIdx.x;
  const int lane = tid & 63;
  const int wid = tid >> 6;
  const int m0 = blockIdx.x * 32;
  const int n0 = blockIdx.y * 64;

  const unsigned short* Ab_h = Ah_ + (size_t)m0 * Kd;
  const unsigned short* Ab_l = Al_ + (size_t)m0 * Kd;
  const unsigned short* Bb_h = Bh_ + (size_t)n0 * Kd;
  const unsigned short* Bb_l = Bl_ + (size_t)n0 * Kd;

  const int srow = lane >> 2;
  const int sk = ((lane & 3) ^ ((lane >> 3) & 3)) * 8;
  const int wm = wid >> 1, wn = wid & 1;
  const int fr = lane & 15;
  const int q = lane >> 4;
  const int fqs = (q ^ ((fr >> 1) & 3)) * 8;

  v4f acc[2];
  acc[0] = (v4f)(0.f);
  acc[1] = (v4f)(0.f);

  auto stage = [&](int b, int k0) {
    #pragma unroll
    for (int u = 0; u < 6; u++) {
      const int i = wid * 6 + u;
      const unsigned short* gs; unsigned short* ls; int slab, seg, rstride;
      if (i < 4)       { gs = Ab_h; ls = smem + b * 2048;          slab = i >> 1;        seg = i & 1;        rstride = 1024; }
      else if (i < 8)  { gs = Ab_l; ls = smem + 4096 + b * 2048;   slab = (i - 4) >> 1;  seg = (i - 4) & 1;  rstride = 1024; }
      else if (i < 16) { gs = Bb_h; ls = smem + 8192 + b * 4096;   slab = (i - 8) >> 2;  seg = (i - 8) & 3;  rstride = 2048; }
      else             { gs = Bb_l; ls = smem + 16384 + b * 4096;  slab = (i - 16) >> 2; seg = (i - 16) & 3; rstride = 2048; }
      gl2lds16(gs + (size_t)(seg * 16 + srow) * Kd + k0 + slab * 32 + sk,
               ls + slab * rstride + seg * 512);
    }
  };

  stage(0, 0);
  int cur = 0;
  for (int k0 = 0; k0 < Kd; k0 += 64) {
    __syncthreads();
    if (k0 + 64 < Kd) stage(cur ^ 1, k0 + 64);

    #pragma unroll
    for (int kk = 0; kk < 2; kk++) {
      const int ar = kk * 1024 + (wm * 16 + fr) * 32 + fqs;
      const v8s ah = *(const v8s*)&smem[cur * 2048 + ar];
      const v8s al = *(const v8s*)&smem[4096 + cur * 2048 + ar];
      #pragma unroll
      for (int nt = 0; nt < 2; nt++) {
        const int br = kk * 2048 + (wn * 32 + nt * 16 + fr) * 32 + fqs;
        const v8s bh = *(const v8s*)&smem[8192 + cur * 4096 + br];
        const v8s bl = *(const v8s*)&smem[16384 + cur * 4096 + br];
        acc[nt] = MFMA16(ah, bh, acc[nt], 0, 0, 0);
        acc[nt] = MFMA16(ah, bl, acc[nt], 0, 0, 0);
        acc[nt] = MFMA16(al, bh, acc[nt], 0, 0, 0);
      }
    }
    cur ^= 1;
  }

  const int col16 = lane & 15;
  #pragma unroll
  for (int nt = 0; nt < 2; nt++) {
    const int col = n0 + wn * 32 + nt * 16 + col16;
    const float bv = bias[col];
    #pragma unroll
    for (int reg = 0; reg < 4; reg++) {
      const int row = m0 + wm * 16 + q * 4 + reg;
      float v = acc[nt][reg] + bv;
      const unsigned short hi = f2bf(v);
      oh[(size_t)row * N + col] = hi;
      ol[(size_t)row * N + col] = f2bf(v - bf2f(hi));
    }
  }
}

// ---------------------------------------------------------------------------
// Kernel 3: VQ via split-bf16 MFMA GEMM — R5 EXACT (best measured: 91.3 µs,
// MfmaUtil 49%, SQ_LDS_BANK_CONFLICT 0; 106.8 µs on a slower container —
// cross-container variance ~15%). DECLARED STRUCTURAL FLOOR. Do not touch.
// score = ||c||^2 - 2*e.c
// ---------------------------------------------------------------------------
__global__ __launch_bounds__(512, 2) void k_vq(const unsigned short* __restrict__ eh,
                                               const unsigned short* __restrict__ el,
                                               const unsigned short* __restrict__ ch,
                                               const unsigned short* __restrict__ cl,
                                               const float* __restrict__ cnorm,
                                               unsigned long long* __restrict__ rowmin) {
  __shared__ unsigned short lds[2 * 32768];   // 128 KB

  const int tid = threadIdx.x;
  const int lane = tid & 63;
  const int wid = tid >> 6;                  // 0..7
  const int bid = blockIdx.x;
  const int x = (bid >> 3) & 7;              // 8 e-tiles (256 rows)
  const int y = (((bid >> 6) & 7) << 3) | (bid & 7);  // 64 cb-tiles (256 rows)
  const int r0 = x * 256;
  const int c0 = y * 256;

  const unsigned short* ehB = eh + (size_t)r0 * DIMC;
  const unsigned short* elB = el + (size_t)r0 * DIMC;
  const unsigned short* chB = ch + (size_t)c0 * DIMC;
  const unsigned short* clB = cl + (size_t)c0 * DIMC;

  const int srow = lane >> 2;                // 0..15
  const int sk = ((lane & 3) ^ ((lane >> 3) & 3)) * 8;   // shorts
  const int wm = wid >> 1;                   // 0..3 (M)
  const int wn = wid & 1;                    // 0..1 (N)
  const int fr = lane & 15;
  const int q = lane >> 4;
  const int fqs = (q ^ ((fr >> 1) & 3)) * 8;

  v4f acc[4][8];
  #pragma unroll
  for (int i = 0; i < 4; i++)
    #pragma unroll
    for (int jj = 0; jj < 8; jj++) acc[i][jj] = (v4f)(0.f);

  const unsigned short* gp[8];
  int lo_[8];
  #pragma unroll
  for (int u = 0; u < 8; u++) {
    const int i = wid * 8 + u;
    const unsigned short* gs; int off, rbase;
    if (i < 16)      { gs = ehB; off = 0;     rbase = i * 16; }
    else if (i < 32) { gs = elB; off = 8192;  rbase = (i - 16) * 16; }
    else if (i < 48) { gs = chB; off = 16384; rbase = (i - 32) * 16; }
    else             { gs = clB; off = 24576; rbase = (i - 48) * 16; }
    gp[u] = gs + (size_t)(rbase + srow) * DIMC + sk;
    lo_[u] = off + rbase * 32;
  }

  auto stage = [&](int buf, int k0) {
    #pragma unroll
    for (int u = 0; u < 8; u++)
      gl2lds16(gp[u] + k0, lds + buf * 32768 + lo_[u]);
  };

  stage(0, 0);
  __syncthreads();

  for (int t = 0; t < 16; ++t) {
    if (t < 15) stage((t + 1) & 1, (t + 1) * 32);

    const unsigned short* base = lds + (t & 1) * 32768;
    v8s ah[4], al[4];
    #pragma unroll
    for (int mt = 0; mt < 4; mt++) {
      const int ar = (wm * 64 + mt * 16 + fr) * 32 + fqs;
      ah[mt] = *(const v8s*)&base[ar];
      al[mt] = *(const v8s*)&base[8192 + ar];
    }
    __builtin_amdgcn_s_setprio(1);
    #pragma unroll
    for (int nt = 0; nt < 8; nt++) {
      const int br = (wn * 128 + nt * 16 + fr) * 32 + fqs;
      const v8s bh = *(const v8s*)&base[16384 + br];
      const v8s bl = *(const v8s*)&base[24576 + br];
      #pragma unroll
      for (int mt = 0; mt < 4; mt++) {
        acc[mt][nt] = MFMA16(ah[mt], bh, acc[mt][nt], 0, 0, 0);
        acc[mt][nt] = MFMA16(ah[mt], bl, acc[mt][nt], 0, 0, 0);
        acc[mt][nt] = MFMA16(al[mt], bh, acc[mt][nt], 0, 0, 0);
      }
    }
    __builtin_amdgcn_s_setprio(0);
    if (t < 15) __syncthreads();
  }

  const int col16 = lane & 15;
  float cn[8];
  #pragma unroll
  for (int nt = 0; nt < 8; nt++) cn[nt] = cnorm[c0 + wn * 128 + nt * 16 + col16];

  #pragma unroll
  for (int mt = 0; mt < 4; mt++) {
    #pragma unroll
    for (int reg = 0; reg < 4; reg++) {
      const int row = r0 + wm * 64 + mt * 16 + q * 4 + reg;
      float best = fmaf(-2.f, acc[mt][0][reg], cn[0]);
      int bid2 = c0 + wn * 128 + col16;
      #pragma unroll
      for (int nt = 1; nt < 8; nt++) {
        const float s = fmaf(-2.f, acc[mt][nt][reg], cn[nt]);
        const int id = c0 + wn * 128 + nt * 16 + col16;
        if (s < best) { best = s; bid2 = id; }
      }
      unsigned long long v =
          ((unsigned long long)f2ord(best) << 32) | (unsigned int)bid2;
      #pragma unroll
      for (int off = 8; off > 0; off >>= 1) {
        const unsigned long long o = __shfl_down(v, off, 16);
        if (o < v) v = o;
      }
      if (col16 == 0) atomicMin(&rowmin[row], v);
    }
  }
}

// ---------------------------------------------------------------------------
// Kernel 4: finalize — ids as float + gather q rows. 4 samples per 256-thr
// block (was 1 per 64-thr block): 512 blocks.
// ---------------------------------------------------------------------------
__global__ __launch_bounds__(256) void k_final(const unsigned long long* __restrict__ rowmin,
                                               const float* __restrict__ cb,
                                               float* __restrict__ out,
                                               int B) {
  const int b = blockIdx.x * 4 + (threadIdx.x >> 6);
  const int t = threadIdx.x & 63;
  const unsigned long long m = rowmin[b];
  const int id = (int)(unsigned int)(m & 0xFFFFFFFFull);
  if (t == 0) out[b] = (float)id;
  float4* q4 = (float4*)(out + B) + b * 128;
  const float4* cb4 = (const float4*)cb + (size_t)id * 128;
  q4[t] = cb4[t];
  q4[t + 64] = cb4[t + 64];
}

// ---------------------------------------------------------------------------
extern "C" void kernel_launch(void* const* d_in, const int* in_sizes, int n_in,
                              void* d_out, int out_size, void* d_ws, size_t ws_size,
                              hipStream_t stream) {
  const int* zt = (const int*)d_in[0];
  const int* ztp = (const int*)d_in[1];
  const float* emb = (const float*)d_in[2];
  const float* w1 = (const float*)d_in[3];
  const float* b1 = (const float*)d_in[4];
  const float* w2 = (const float*)d_in[5];
  const float* b2 = (const float*)d_in[6];
  const float* cb = (const float*)d_in[7];
  float* out = (float*)d_out;

  const int B = in_sizes[0] / TOK;        // 2048
  const int A = in_sizes[7] / DIMC;       // 16384

  char* p = (char*)d_ws;
  unsigned short* hh = (unsigned short*)p;  p += (size_t)B * 1024 * 2;
  unsigned short* hl = (unsigned short*)p;  p += (size_t)B * 1024 * 2;
  unsigned short* w1th = (unsigned short*)p; p += (size_t)512 * 1024 * 2;
  unsigned short* w1tl = (unsigned short*)p; p += (size_t)512 * 1024 * 2;
  unsigned short* w2th = (unsigned short*)p; p += (size_t)512 * 512 * 2;
  unsigned short* w2tl = (unsigned short*)p; p += (size_t)512 * 512 * 2;
  unsigned short* h1h = (unsigned short*)p; p += (size_t)B * DIMC * 2;
  unsigned short* h1l = (unsigned short*)p; p += (size_t)B * DIMC * 2;
  unsigned short* eh = (unsigned short*)p;  p += (size_t)B * DIMC * 2;
  unsigned short* el = (unsigned short*)p;  p += (size_t)B * DIMC * 2;
  unsigned short* ch = (unsigned short*)p;  p += (size_t)A * DIMC * 2;
  unsigned short* cl = (unsigned short*)p;  p += (size_t)A * DIMC * 2;
  float* cnorm = (float*)p;                 p += (size_t)A * 4;
  unsigned long long* rowmin = (unsigned long long*)p;

  k_prep<<<2560, 256, 0, stream>>>(zt, ztp, emb, hh, hl, rowmin, w1, w1th, w1tl);
  k_gemm1_fused<<<768 + A / 4, 256, 0, stream>>>(hh, hl, w1th, w1tl, b1, h1h, h1l,
                                                 w2, w2th, w2tl, cb, ch, cl, cnorm);
  k_gemm2<<<dim3(B / 32, 512 / 64), 256, 0, stream>>>(h1h, h1l, w2th, w2tl, b2, eh, el);
  k_vq<<<(B / 256) * (A / 256), 512, 0, stream>>>(eh, el, ch, cl, cnorm, rowmin);
  k_final<<<B / 4, 256, 0, stream>>>(rowmin, cb, out, B);
}